// Round 3
// baseline (340.149 us; speedup 1.0000x reference)
//
#include <hip/hip_runtime.h>
#include <hip/hip_cooperative_groups.h>

namespace cg = cooperative_groups;

static constexpr float kThresh = 0.01f;
static constexpr int FBLOCKS = 1024;   // fused cooperative grid: 4 blocks/CU, 16 waves/CU
static constexpr int RBLOCKS = 1024;   // fallback stage-1 grid

// Monotone float <-> uint key: k(a) < k(b)  <=>  a < b  (for non-NaN floats)
__device__ __forceinline__ unsigned fkey(float f) {
    unsigned u = __float_as_uint(f);
    return (u & 0x80000000u) ? ~u : (u | 0x80000000u);
}
__device__ __forceinline__ float unkey(unsigned k) {
    unsigned u = (k & 0x80000000u) ? (k & 0x7fffffffu) : ~k;
    return __uint_as_float(u);
}

__device__ __forceinline__ void acc_one(float x, unsigned& smin, unsigned& smax,
                                        unsigned& lmin, unsigned& lmax) {
    unsigned k = fkey(x);
    if (fabsf(x) > kThresh) {
        lmin = min(lmin, k);
        lmax = max(lmax, k);
    } else {
        smin = min(smin, k);
        smax = max(smax, k);
    }
}

__device__ __forceinline__ void acc4(const float4& v, unsigned& smin, unsigned& smax,
                                     unsigned& lmin, unsigned& lmax) {
    acc_one(v.x, smin, smax, lmin, lmax);
    acc_one(v.y, smin, smax, lmin, lmax);
    acc_one(v.z, smin, smax, lmin, lmax);
    acc_one(v.w, smin, smax, lmin, lmax);
}

__device__ __forceinline__ void wave_reduce4(unsigned& smin, unsigned& smax,
                                             unsigned& lmin, unsigned& lmax) {
    #pragma unroll
    for (int off = 32; off > 0; off >>= 1) {
        smin = min(smin, (unsigned)__shfl_down((int)smin, off));
        smax = max(smax, (unsigned)__shfl_down((int)smax, off));
        lmin = min(lmin, (unsigned)__shfl_down((int)lmin, off));
        lmax = max(lmax, (unsigned)__shfl_down((int)lmax, off));
    }
}

__device__ __forceinline__ float deq1(float x, float smin, float ssc, float sis, bool sv,
                                      float lmin, float lsc, float lis, bool lv) {
    bool large = fabsf(x) > kThresh;
    float bmin = large ? lmin : smin;
    float sc   = large ? lsc : ssc;
    float is   = large ? lis : sis;
    bool  v    = large ? lv : sv;
    float q = rintf((x - bmin) * sc);   // round((x-bmin)/denom*levels), half-to-even
    float d = fmaf(q, is, bmin);        // q/levels*denom + bmin
    return v ? d : x;
}

// ============ fused cooperative kernel ============
// ws layout (unsigned): [0..3] unused here; [4 + 4*b .. ] per-block partials.
__global__ __launch_bounds__(256) void kv_fused(const float* __restrict__ in,
                                                float* __restrict__ out, int n,
                                                unsigned* __restrict__ ws) {
    unsigned* __restrict__ partials = ws + 4;
    const int n4 = n >> 2;
    const float4* __restrict__ in4 = (const float4*)in;
    const int stride = gridDim.x * blockDim.x;
    const int i0 = blockIdx.x * blockDim.x + threadIdx.x;

    // ---- phase A: grid-stride min/max accumulate (x2 unrolled loads) ----
    unsigned smin = 0xFFFFFFFFu, smax = 0u, lmin = 0xFFFFFFFFu, lmax = 0u;
    for (int i = i0; i < n4; i += 2 * stride) {
        float4 a = in4[i];
        int j = i + stride;
        float4 b = (j < n4) ? in4[j] : a;   // duplicate is idempotent for min/max
        acc4(a, smin, smax, lmin, lmax);
        acc4(b, smin, smax, lmin, lmax);
    }
    for (int i = (n4 << 2) + i0; i < n; i += stride) {
        acc_one(in[i], smin, smax, lmin, lmax);
    }

    wave_reduce4(smin, smax, lmin, lmax);

    __shared__ unsigned ls[4][4];
    const int wave = threadIdx.x >> 6;
    if ((threadIdx.x & 63) == 0) {
        ls[wave][0] = smin; ls[wave][1] = smax; ls[wave][2] = lmin; ls[wave][3] = lmax;
    }
    __syncthreads();
    if (threadIdx.x == 0) {
        unsigned a = ls[0][0], b = ls[0][1], c = ls[0][2], d = ls[0][3];
        #pragma unroll
        for (int w = 1; w < 4; ++w) {
            a = min(a, ls[w][0]); b = max(b, ls[w][1]);
            c = min(c, ls[w][2]); d = max(d, ls[w][3]);
        }
        partials[blockIdx.x * 4 + 0] = a;
        partials[blockIdx.x * 4 + 1] = b;
        partials[blockIdx.x * 4 + 2] = c;
        partials[blockIdx.x * 4 + 3] = d;
    }

    cg::this_grid().sync();   // device-scope fence + grid barrier

    // ---- phase B: every block redundantly folds all partials (no 2nd sync) ----
    unsigned fa = 0xFFFFFFFFu, fb = 0u, fc = 0xFFFFFFFFu, fd = 0u;
    for (int i = threadIdx.x; i < (int)gridDim.x; i += blockDim.x) {
        fa = min(fa, partials[4 * i + 0]);
        fb = max(fb, partials[4 * i + 1]);
        fc = min(fc, partials[4 * i + 2]);
        fd = max(fd, partials[4 * i + 3]);
    }
    wave_reduce4(fa, fb, fc, fd);
    __syncthreads();   // protect ls[] reuse
    if ((threadIdx.x & 63) == 0) {
        ls[wave][0] = fa; ls[wave][1] = fb; ls[wave][2] = fc; ls[wave][3] = fd;
    }
    __syncthreads();

    __shared__ float p_smin, p_ssc, p_sis, p_lmin, p_lsc, p_lis;
    __shared__ int p_sv, p_lv;
    if (threadIdx.x == 0) {
        unsigned a = ls[0][0], b = ls[0][1], c = ls[0][2], d = ls[0][3];
        #pragma unroll
        for (int w = 1; w < 4; ++w) {
            a = min(a, ls[w][0]); b = max(b, ls[w][1]);
            c = min(c, ls[w][2]); d = max(d, ls[w][3]);
        }
        bool sv = a < b, lv = c < d;     // valid = has_any && (bmax != bmin)
        float smn = unkey(a), lmn = unkey(c);
        float sden = sv ? (unkey(b) - smn) : 1.0f;
        float lden = lv ? (unkey(d) - lmn) : 1.0f;
        p_smin = smn; p_ssc = 15.0f / sden;  p_sis = sden / 15.0f;  p_sv = sv;
        p_lmin = lmn; p_lsc = 255.0f / lden; p_lis = lden / 255.0f; p_lv = lv;
    }
    __syncthreads();

    const float smn = p_smin, ssc = p_ssc, sis = p_sis;
    const float lmn = p_lmin, lsc = p_lsc, lis = p_lis;
    const bool sv = p_sv != 0, lv = p_lv != 0;

    // ---- phase C: grid-stride dequant (input is L3-warm from phase A) ----
    float4* __restrict__ out4 = (float4*)out;
    for (int i = i0; i < n4; i += stride) {
        float4 v = in4[i];
        float4 r;
        r.x = deq1(v.x, smn, ssc, sis, sv, lmn, lsc, lis, lv);
        r.y = deq1(v.y, smn, ssc, sis, sv, lmn, lsc, lis, lv);
        r.z = deq1(v.z, smn, ssc, sis, sv, lmn, lsc, lis, lv);
        r.w = deq1(v.w, smn, ssc, sis, sv, lmn, lsc, lis, lv);
        out4[i] = r;
    }
    for (int i = (n4 << 2) + i0; i < n; i += stride) {
        out[i] = deq1(in[i], smn, ssc, sis, sv, lmn, lsc, lis, lv);
    }
}

// ============ fallback 3-kernel path (round-2 proven) ============
__global__ __launch_bounds__(256) void kv_partial(const float* __restrict__ in, int n,
                                                  unsigned* __restrict__ partials) {
    unsigned smin = 0xFFFFFFFFu, smax = 0u, lmin = 0xFFFFFFFFu, lmax = 0u;
    const int n4 = n >> 2;
    const float4* __restrict__ in4 = (const float4*)in;
    const int stride = gridDim.x * blockDim.x;
    for (int i = blockIdx.x * blockDim.x + threadIdx.x; i < n4; i += stride) {
        float4 v = in4[i];
        acc4(v, smin, smax, lmin, lmax);
    }
    for (int i = (n4 << 2) + blockIdx.x * blockDim.x + threadIdx.x; i < n; i += stride) {
        acc_one(in[i], smin, smax, lmin, lmax);
    }
    wave_reduce4(smin, smax, lmin, lmax);
    __shared__ unsigned ls[4][4];
    const int wave = threadIdx.x >> 6;
    if ((threadIdx.x & 63) == 0) {
        ls[wave][0] = smin; ls[wave][1] = smax; ls[wave][2] = lmin; ls[wave][3] = lmax;
    }
    __syncthreads();
    if (threadIdx.x == 0) {
        unsigned a = ls[0][0], b = ls[0][1], c = ls[0][2], d = ls[0][3];
        #pragma unroll
        for (int w = 1; w < 4; ++w) {
            a = min(a, ls[w][0]); b = max(b, ls[w][1]);
            c = min(c, ls[w][2]); d = max(d, ls[w][3]);
        }
        partials[blockIdx.x * 4 + 0] = a;
        partials[blockIdx.x * 4 + 1] = b;
        partials[blockIdx.x * 4 + 2] = c;
        partials[blockIdx.x * 4 + 3] = d;
    }
}

__global__ __launch_bounds__(256) void kv_final(const unsigned* __restrict__ partials,
                                                unsigned* __restrict__ ws) {
    unsigned smin = 0xFFFFFFFFu, smax = 0u, lmin = 0xFFFFFFFFu, lmax = 0u;
    for (int i = threadIdx.x; i < RBLOCKS; i += 256) {
        smin = min(smin, partials[4 * i + 0]);
        smax = max(smax, partials[4 * i + 1]);
        lmin = min(lmin, partials[4 * i + 2]);
        lmax = max(lmax, partials[4 * i + 3]);
    }
    wave_reduce4(smin, smax, lmin, lmax);
    __shared__ unsigned ls[4][4];
    const int wave = threadIdx.x >> 6;
    if ((threadIdx.x & 63) == 0) {
        ls[wave][0] = smin; ls[wave][1] = smax; ls[wave][2] = lmin; ls[wave][3] = lmax;
    }
    __syncthreads();
    if (threadIdx.x == 0) {
        unsigned a = ls[0][0], b = ls[0][1], c = ls[0][2], d = ls[0][3];
        #pragma unroll
        for (int w = 1; w < 4; ++w) {
            a = min(a, ls[w][0]); b = max(b, ls[w][1]);
            c = min(c, ls[w][2]); d = max(d, ls[w][3]);
        }
        ws[0] = a; ws[1] = b; ws[2] = c; ws[3] = d;
    }
}

__global__ __launch_bounds__(256) void kv_dequant(const float* __restrict__ in,
                                                  float* __restrict__ out, int n,
                                                  const unsigned* __restrict__ ws) {
    const unsigned sk0 = ws[0], sk1 = ws[1], lk0 = ws[2], lk1 = ws[3];
    const bool sv = sk0 < sk1;
    const bool lv = lk0 < lk1;
    const float smin = unkey(sk0);
    const float sden = sv ? (unkey(sk1) - smin) : 1.0f;
    const float lmin = unkey(lk0);
    const float lden = lv ? (unkey(lk1) - lmin) : 1.0f;
    const float ssc = 15.0f / sden,  sis = sden / 15.0f;
    const float lsc = 255.0f / lden, lis = lden / 255.0f;

    const int n4 = n >> 2;
    const int i = blockIdx.x * blockDim.x + threadIdx.x;
    const float4* __restrict__ in4 = (const float4*)in;
    float4* __restrict__ out4 = (float4*)out;
    if (i < n4) {
        float4 v = in4[i];
        float4 r;
        r.x = deq1(v.x, smin, ssc, sis, sv, lmin, lsc, lis, lv);
        r.y = deq1(v.y, smin, ssc, sis, sv, lmin, lsc, lis, lv);
        r.z = deq1(v.z, smin, ssc, sis, sv, lmin, lsc, lis, lv);
        r.w = deq1(v.w, smin, ssc, sis, sv, lmin, lsc, lis, lv);
        out4[i] = r;
    }
    const int tail = n - (n4 << 2);
    if (i < tail) {
        int j = (n4 << 2) + i;
        out[j] = deq1(in[j], smin, ssc, sis, sv, lmin, lsc, lis, lv);
    }
}

extern "C" void kernel_launch(void* const* d_in, const int* in_sizes, int n_in,
                              void* d_out, int out_size, void* d_ws, size_t ws_size,
                              hipStream_t stream) {
    const float* in = (const float*)d_in[0];
    float* out = (float*)d_out;
    unsigned* ws = (unsigned*)d_ws;
    const int n = in_sizes[0];

    const size_t ws_needed = sizeof(unsigned) * (4 + 4 * (size_t)FBLOCKS);
    bool coop_ok = ws_size >= ws_needed;
    if (coop_ok) {
        void* args[] = {(void*)&in, (void*)&out, (void*)&n, (void*)&ws};
        hipError_t err = hipLaunchCooperativeKernel((void*)kv_fused, dim3(FBLOCKS),
                                                    dim3(256), args, 0, stream);
        coop_ok = (err == hipSuccess);
        if (!coop_ok) (void)hipGetLastError();   // clear sticky error
    }
    if (!coop_ok) {
        // Proven 3-kernel path; stage partials at the front of d_out (fully
        // overwritten by kv_dequant afterwards, stream-ordered).
        unsigned* partials = (unsigned*)out;
        kv_partial<<<RBLOCKS, 256, 0, stream>>>(in, n, partials);
        kv_final<<<1, 256, 0, stream>>>(partials, ws);
        const int n4 = n >> 2;
        int dblocks = (n4 + 255) / 256;
        if (dblocks < 1) dblocks = 1;
        kv_dequant<<<dblocks, 256, 0, stream>>>(in, out, n, ws);
    }
}

// Round 5
// 252.530 us; speedup vs baseline: 1.3470x; 1.3470x over previous
//
#include <hip/hip_runtime.h>

static constexpr float kThresh = 0.01f;
static constexpr int RBLOCKS = 2048;   // stage-1 grid: 8 blocks/CU

typedef float floatx4 __attribute__((ext_vector_type(4)));   // native vec for nontemporal builtin

// Monotone float <-> uint key: k(a) < k(b)  <=>  a < b  (for non-NaN floats)
__device__ __forceinline__ unsigned fkey(float f) {
    unsigned u = __float_as_uint(f);
    return (u & 0x80000000u) ? ~u : (u | 0x80000000u);
}
__device__ __forceinline__ float unkey(unsigned k) {
    unsigned u = (k & 0x80000000u) ? (k & 0x7fffffffu) : ~k;
    return __uint_as_float(u);
}

__device__ __forceinline__ void acc_one(float x, unsigned& smin, unsigned& smax,
                                        unsigned& lmin, unsigned& lmax) {
    unsigned k = fkey(x);
    if (fabsf(x) > kThresh) {
        lmin = min(lmin, k);
        lmax = max(lmax, k);
    } else {
        smin = min(smin, k);
        smax = max(smax, k);
    }
}

__device__ __forceinline__ void acc4(const float4& v, unsigned& smin, unsigned& smax,
                                     unsigned& lmin, unsigned& lmax) {
    acc_one(v.x, smin, smax, lmin, lmax);
    acc_one(v.y, smin, smax, lmin, lmax);
    acc_one(v.z, smin, smax, lmin, lmax);
    acc_one(v.w, smin, smax, lmin, lmax);
}

__device__ __forceinline__ void wave_reduce4(unsigned& smin, unsigned& smax,
                                             unsigned& lmin, unsigned& lmax) {
    #pragma unroll
    for (int off = 32; off > 0; off >>= 1) {
        smin = min(smin, (unsigned)__shfl_down((int)smin, off));
        smax = max(smax, (unsigned)__shfl_down((int)smax, off));
        lmin = min(lmin, (unsigned)__shfl_down((int)lmin, off));
        lmax = max(lmax, (unsigned)__shfl_down((int)lmax, off));
    }
}

// Stage 1: per-block min/max partials, no global atomics, x4 independent loads.
__global__ __launch_bounds__(256) void kv_partial(const float* __restrict__ in, int n,
                                                  unsigned* __restrict__ partials) {
    unsigned smin = 0xFFFFFFFFu, smax = 0u, lmin = 0xFFFFFFFFu, lmax = 0u;
    const int n4 = n >> 2;
    const float4* __restrict__ in4 = (const float4*)in;
    const int stride = gridDim.x * blockDim.x;
    const int i0 = blockIdx.x * blockDim.x + threadIdx.x;

    for (int i = i0; i < n4; i += 4 * stride) {
        int i1 = i + stride, i2 = i + 2 * stride, i3 = i + 3 * stride;
        float4 a = in4[i];
        float4 b = (i1 < n4) ? in4[i1] : a;   // duplicate is idempotent for min/max
        float4 c = (i2 < n4) ? in4[i2] : a;
        float4 d = (i3 < n4) ? in4[i3] : a;
        acc4(a, smin, smax, lmin, lmax);
        acc4(b, smin, smax, lmin, lmax);
        acc4(c, smin, smax, lmin, lmax);
        acc4(d, smin, smax, lmin, lmax);
    }
    for (int i = (n4 << 2) + i0; i < n; i += stride) {
        acc_one(in[i], smin, smax, lmin, lmax);
    }

    wave_reduce4(smin, smax, lmin, lmax);

    __shared__ unsigned ls[4][4];
    const int wave = threadIdx.x >> 6;
    if ((threadIdx.x & 63) == 0) {
        ls[wave][0] = smin; ls[wave][1] = smax; ls[wave][2] = lmin; ls[wave][3] = lmax;
    }
    __syncthreads();
    if (threadIdx.x == 0) {
        unsigned a = ls[0][0], b = ls[0][1], c = ls[0][2], d = ls[0][3];
        #pragma unroll
        for (int w = 1; w < 4; ++w) {
            a = min(a, ls[w][0]); b = max(b, ls[w][1]);
            c = min(c, ls[w][2]); d = max(d, ls[w][3]);
        }
        partials[blockIdx.x * 4 + 0] = a;
        partials[blockIdx.x * 4 + 1] = b;
        partials[blockIdx.x * 4 + 2] = c;
        partials[blockIdx.x * 4 + 3] = d;
    }
}

// Stage 2: one block folds RBLOCKS partial sets into ws[0..3].
__global__ __launch_bounds__(256) void kv_final(const unsigned* __restrict__ partials,
                                                unsigned* __restrict__ ws) {
    unsigned smin = 0xFFFFFFFFu, smax = 0u, lmin = 0xFFFFFFFFu, lmax = 0u;
    for (int i = threadIdx.x; i < RBLOCKS; i += 256) {
        smin = min(smin, partials[4 * i + 0]);
        smax = max(smax, partials[4 * i + 1]);
        lmin = min(lmin, partials[4 * i + 2]);
        lmax = max(lmax, partials[4 * i + 3]);
    }
    wave_reduce4(smin, smax, lmin, lmax);
    __shared__ unsigned ls[4][4];
    const int wave = threadIdx.x >> 6;
    if ((threadIdx.x & 63) == 0) {
        ls[wave][0] = smin; ls[wave][1] = smax; ls[wave][2] = lmin; ls[wave][3] = lmax;
    }
    __syncthreads();
    if (threadIdx.x == 0) {
        unsigned a = ls[0][0], b = ls[0][1], c = ls[0][2], d = ls[0][3];
        #pragma unroll
        for (int w = 1; w < 4; ++w) {
            a = min(a, ls[w][0]); b = max(b, ls[w][1]);
            c = min(c, ls[w][2]); d = max(d, ls[w][3]);
        }
        ws[0] = a; ws[1] = b; ws[2] = c; ws[3] = d;
    }
}

__device__ __forceinline__ float deq1(float x, float smin, float ssc, float sis, bool sv,
                                      float lmin, float lsc, float lis, bool lv) {
    bool large = fabsf(x) > kThresh;
    float bmin = large ? lmin : smin;
    float sc   = large ? lsc : ssc;
    float is   = large ? lis : sis;
    bool  v    = large ? lv : sv;
    float q = rintf((x - bmin) * sc);   // round((x-bmin)/denom*levels), half-to-even
    float d = fmaf(q, is, bmin);        // q/levels*denom + bmin
    return v ? d : x;
}

// Stage 3: one-shot elementwise dequant; nontemporal stores (write-once output).
__global__ __launch_bounds__(256) void kv_dequant(const float* __restrict__ in,
                                                  float* __restrict__ out, int n,
                                                  const unsigned* __restrict__ ws) {
    const unsigned sk0 = ws[0], sk1 = ws[1], lk0 = ws[2], lk1 = ws[3];
    const bool sv = sk0 < sk1;     // valid = has_any && (bmax != bmin)
    const bool lv = lk0 < lk1;
    const float smin = unkey(sk0);
    const float sden = sv ? (unkey(sk1) - smin) : 1.0f;
    const float lmin = unkey(lk0);
    const float lden = lv ? (unkey(lk1) - lmin) : 1.0f;
    const float ssc = 15.0f / sden,  sis = sden / 15.0f;
    const float lsc = 255.0f / lden, lis = lden / 255.0f;

    const int n4 = n >> 2;
    const int i = blockIdx.x * blockDim.x + threadIdx.x;
    const float4* __restrict__ in4 = (const float4*)in;
    floatx4* __restrict__ out4 = (floatx4*)out;
    if (i < n4) {
        float4 v = in4[i];
        floatx4 r;
        r.x = deq1(v.x, smin, ssc, sis, sv, lmin, lsc, lis, lv);
        r.y = deq1(v.y, smin, ssc, sis, sv, lmin, lsc, lis, lv);
        r.z = deq1(v.z, smin, ssc, sis, sv, lmin, lsc, lis, lv);
        r.w = deq1(v.w, smin, ssc, sis, sv, lmin, lsc, lis, lv);
        __builtin_nontemporal_store(r, &out4[i]);
    }
    const int tail = n - (n4 << 2);
    if (i < tail) {
        int j = (n4 << 2) + i;
        out[j] = deq1(in[j], smin, ssc, sis, sv, lmin, lsc, lis, lv);
    }
}

extern "C" void kernel_launch(void* const* d_in, const int* in_sizes, int n_in,
                              void* d_out, int out_size, void* d_ws, size_t ws_size,
                              hipStream_t stream) {
    const float* in = (const float*)d_in[0];
    float* out = (float*)d_out;
    unsigned* ws = (unsigned*)d_ws;
    const int n = in_sizes[0];

    // Partials live in d_ws past the 4 result slots (RBLOCKS*4*4B = 32 KB).
    unsigned* partials = ws + 4;
    // d_ws is guaranteed scratch; if it were ever too small, fall back to
    // staging partials at the front of d_out (dequant overwrites it later).
    if (ws_size < sizeof(unsigned) * (4 + 4 * (size_t)RBLOCKS)) {
        partials = (unsigned*)out;
    }

    kv_partial<<<RBLOCKS, 256, 0, stream>>>(in, n, partials);
    kv_final<<<1, 256, 0, stream>>>(partials, ws);

    const int n4 = n >> 2;
    int dblocks = (n4 + 255) / 256;
    if (dblocks < 1) dblocks = 1;
    kv_dequant<<<dblocks, 256, 0, stream>>>(in, out, n, ws);
}